// Round 1
// baseline (666.271 us; speedup 1.0000x reference)
//
#include <hip/hip_runtime.h>
#include <hip/hip_bf16.h>
#include <math.h>

#define VOCABN 32000
#define EDIM 256
#define HDIM 256
#define BDIM 64
#define TDIM 2048
#define NC 64                 // time chunks
#define TC (TDIM / NC)        // 32 timesteps per chunk
#define HT 32                 // h per block (16 pairs of 2)
#define NB 4                  // batches per thread (bl, bl+16, bl+32, bl+48)

// Kernel 1: fused embedding-gather + gate GEMM (z,f) + activations + in-chunk
// linear-recurrence composition. Each block: 32 h values x all 64 batches x
// one chunk of 32 timesteps. Writes per-chunk (A,B) with c_out = A*c_in + B.
__global__ __launch_bounds__(256) void qrnn_gates_scan(
    const int* __restrict__ X, const float* __restrict__ emb,
    const float* __restrict__ Wq, const float* __restrict__ bq,
    float* __restrict__ wsA, float* __restrict__ wsB)
{
    // LDS W tile: [e][4*p + k], k: 0->z(h0+2p), 1->z(h0+2p+1), 2->f(h0+2p), 3->f(h0+2p+1)
    __shared__ float Wlds[EDIM * 64];   // 64 KB
    const int tid   = threadIdx.x;
    const int h0    = blockIdx.x * HT;
    const int chunk = blockIdx.y;

    for (int i = tid; i < EDIM * 64; i += 256) {
        int e = i >> 6, j = i & 63;
        int p = j >> 2, k = j & 3;
        int hh = h0 + 2 * p + (k & 1);
        int col = (k < 2) ? hh : (HDIM + hh);
        Wlds[i] = Wq[e * (3 * HDIM) + col];
    }
    __syncthreads();

    const int p  = tid & 15;       // h-pair index
    const int bl = tid >> 4;       // 0..15
    const int h  = h0 + 2 * p;

    const float bz0 = bq[h],        bz1 = bq[h + 1];
    const float bf0 = bq[HDIM + h], bf1 = bq[HDIM + h + 1];

    int bidx[NB];
    const int* Xp[NB];
#pragma unroll
    for (int j = 0; j < NB; ++j) {
        bidx[j] = bl + 16 * j;
        Xp[j]   = X + bidx[j] * TDIM;
    }

    float A[NB][2], Bs[NB][2];
#pragma unroll
    for (int j = 0; j < NB; ++j) {
        A[j][0] = 1.f; A[j][1] = 1.f;
        Bs[j][0] = 0.f; Bs[j][1] = 0.f;
    }

    const int t0 = chunk * TC;
    const float4* __restrict__ W4 = (const float4*)Wlds;  // [EDIM][16]

    for (int t = 0; t < TC; ++t) {
        const float* xr[NB];
#pragma unroll
        for (int j = 0; j < NB; ++j)
            xr[j] = emb + (size_t)Xp[j][t0 + t] * EDIM;

        float acc[NB][4];
#pragma unroll
        for (int j = 0; j < NB; ++j)
            acc[j][0] = acc[j][1] = acc[j][2] = acc[j][3] = 0.f;

        for (int e = 0; e < EDIM; e += 4) {
            float4 xv[NB];
#pragma unroll
            for (int j = 0; j < NB; ++j)
                xv[j] = *(const float4*)(xr[j] + e);
#pragma unroll
            for (int u = 0; u < 4; ++u) {
                float4 w = W4[(e + u) * 16 + p];
#pragma unroll
                for (int j = 0; j < NB; ++j) {
                    float xs = (u == 0) ? xv[j].x : (u == 1) ? xv[j].y
                             : (u == 2) ? xv[j].z : xv[j].w;
                    acc[j][0] = fmaf(xs, w.x, acc[j][0]);
                    acc[j][1] = fmaf(xs, w.y, acc[j][1]);
                    acc[j][2] = fmaf(xs, w.z, acc[j][2]);
                    acc[j][3] = fmaf(xs, w.w, acc[j][3]);
                }
            }
        }

#pragma unroll
        for (int j = 0; j < NB; ++j) {
            float z0 = tanhf(acc[j][0] + bz0);
            float z1 = tanhf(acc[j][1] + bz1);
            float f0 = 1.f / (1.f + expf(-(acc[j][2] + bf0)));
            float f1 = 1.f / (1.f + expf(-(acc[j][3] + bf1)));
            A[j][0] *= f0;
            A[j][1] *= f1;
            Bs[j][0] = fmaf(f0, Bs[j][0], (1.f - f0) * z0);
            Bs[j][1] = fmaf(f1, Bs[j][1], (1.f - f1) * z1);
        }
    }

#pragma unroll
    for (int j = 0; j < NB; ++j) {
        size_t base = ((size_t)chunk * BDIM + bidx[j]) * HDIM + h;
        wsA[base]     = A[j][0];
        wsA[base + 1] = A[j][1];
        wsB[base]     = Bs[j][0];
        wsB[base + 1] = Bs[j][1];
    }
}

// Kernel 2: combine chunk (A,B) pairs in time order, compute o at t=T-1,
// hn = o * c_last, then out[b] = sum_h hn*W_out + b_out.
__global__ __launch_bounds__(256) void qrnn_combine(
    const float* __restrict__ wsA, const float* __restrict__ wsB,
    const float* __restrict__ c0, const int* __restrict__ X,
    const float* __restrict__ emb, const float* __restrict__ Wq,
    const float* __restrict__ bq, const float* __restrict__ Wout,
    const float* __restrict__ bout, float* __restrict__ out)
{
    const int b = blockIdx.x;
    const int h = threadIdx.x;

    float c = c0[b * HDIM + h];
    for (int ci = 0; ci < NC; ++ci) {
        size_t base = ((size_t)ci * BDIM + b) * HDIM + h;
        c = fmaf(wsA[base], c, wsB[base]);
    }

    __shared__ float xs[EDIM];
    int idx = X[b * TDIM + (TDIM - 1)];
    xs[h] = emb[(size_t)idx * EDIM + h];
    __syncthreads();

    float acc = 0.f;
#pragma unroll 8
    for (int e = 0; e < EDIM; ++e)
        acc = fmaf(xs[e], Wq[e * (3 * HDIM) + 2 * HDIM + h], acc);

    float o  = 1.f / (1.f + expf(-(acc + bq[2 * HDIM + h])));
    float hn = o * c;

    __shared__ float red[HDIM];
    red[h] = hn * Wout[h];
    __syncthreads();
    for (int s = HDIM / 2; s > 0; s >>= 1) {
        if (h < s) red[h] += red[h + s];
        __syncthreads();
    }
    if (h == 0) out[b] = red[0] + bout[0];
}

extern "C" void kernel_launch(void* const* d_in, const int* in_sizes, int n_in,
                              void* d_out, int out_size, void* d_ws, size_t ws_size,
                              hipStream_t stream) {
    const int*   X    = (const int*)d_in[0];
    const float* emb  = (const float*)d_in[1];
    const float* Wq   = (const float*)d_in[2];
    const float* bq   = (const float*)d_in[3];
    const float* c0   = (const float*)d_in[4];
    const float* Wout = (const float*)d_in[5];
    const float* bout = (const float*)d_in[6];
    float* out = (float*)d_out;

    float* wsA = (float*)d_ws;                       // [NC][B][H]
    float* wsB = wsA + (size_t)NC * BDIM * HDIM;     // [NC][B][H]  (8 MB total)

    dim3 g1(HDIM / HT, NC);   // 8 x 64 = 512 blocks
    qrnn_gates_scan<<<g1, 256, 0, stream>>>(X, emb, Wq, bq, wsA, wsB);
    qrnn_combine<<<BDIM, 256, 0, stream>>>(wsA, wsB, c0, X, emb, Wq, bq, Wout, bout, out);
}

// Round 2
// 184.465 us; speedup vs baseline: 3.6119x; 3.6119x over previous
//
#include <hip/hip_runtime.h>
#include <hip/hip_bf16.h>
#include <math.h>

#define EDIM 256
#define HDIM 256
#define BDIM 64
#define TDIM 2048
#define NC   64
#define TC   32
#define ROWPAD 40   // shorts per 32-k row chunk (80 B: 16B-aligned b128, uniform 2-way banks)

typedef __attribute__((ext_vector_type(8)))  short  short8;
typedef __attribute__((ext_vector_type(4)))  float  floatx4;
typedef __attribute__((ext_vector_type(4)))  unsigned int uintx4;

__device__ __forceinline__ unsigned short f2bf(float f) {
    unsigned int u = __float_as_uint(f);
    u += 0x7FFFu + ((u >> 16) & 1u);      // RNE
    return (unsigned short)(u >> 16);
}
__device__ __forceinline__ unsigned int pk2(float a, float b) {
    return (unsigned int)f2bf(a) | ((unsigned int)f2bf(b) << 16);
}
__device__ __forceinline__ float sigm(float x) {
    return __builtin_amdgcn_rcpf(1.f + __expf(-x));
}
__device__ __forceinline__ float tanh_fast(float x) {
    return fmaf(-2.f, __builtin_amdgcn_rcpf(1.f + __expf(2.f * x)), 1.f);
}

// Wt[col][k] = bf16(Wq[k][col]), col 0..511 (z: h, f: 256+h). o-cols unused here.
__global__ __launch_bounds__(256) void conv_w(const float* __restrict__ Wq,
                                              unsigned short* __restrict__ Wt) {
    int col = blockIdx.x;
    int k   = threadIdx.x;
    Wt[col * EDIM + k] = f2bf(Wq[k * (3 * HDIM) + col]);
}

__global__ __launch_bounds__(256) void conv_emb(const float* __restrict__ emb,
                                                unsigned short* __restrict__ ebf) {
    size_t i = ((size_t)blockIdx.x * 256 + threadIdx.x) * 4;
    floatx4 v = *(const floatx4*)(emb + i);
    uint2 o; o.x = pk2(v.x, v.y); o.y = pk2(v.z, v.w);
    *(uint2*)(ebf + i) = o;
}

// Main: block = (chunk of 32 t) x (4 batches) x (64 h). GEMM 128m x 128n x 256k,
// m = b_local*32 + t, n<64: z col h, n>=64: f col h. Wave w owns b_local = w
// (m-tiles 2w, 2w+1) and all 8 n-tiles -> z,f for (t,b,h) are lane-co-located.
template<bool EMBBF>
__global__ __launch_bounds__(256) void qrnn_mfma(
    const int* __restrict__ X, const float* __restrict__ emb,
    const unsigned short* __restrict__ ebf, const unsigned short* __restrict__ Wt,
    const float* __restrict__ bq, float* __restrict__ wsA, float* __restrict__ wsB)
{
    __shared__ __align__(16) short Ab[2][128 * ROWPAD];
    __shared__ __align__(16) short Bb[2][128 * ROWPAD];

    const int tid = threadIdx.x;
    const int chunk = blockIdx.x, bg = blockIdx.y, hg = blockIdx.z;
    const int t0 = chunk * TC;

    // staging: 2 threads per row (r 0..127), 32 B each
    const int r = tid & 127, half = tid >> 7;
    const int xidx = X[(bg * 4 + (r >> 5)) * TDIM + t0 + (r & 31)];
    const size_t a_base = (size_t)xidx * EDIM + half * 16;
    const int wrow = hg * 64 + (r & 63) + ((r >= 64) ? 256 : 0);
    const size_t b_base = (size_t)wrow * EDIM + half * 16;
    const int lw = r * ROWPAD + half * 16;

    const int lane = tid & 63, w = tid >> 6;
    const int col = lane & 15, q = lane >> 4;

    uintx4 pa0, pa1, pb0, pb1;
    auto fetch = [&](int ks) {
        const unsigned short* wp = Wt + b_base + ks * 32;
        pb0 = *(const uintx4*)wp; pb1 = *(const uintx4*)(wp + 8);
        if constexpr (EMBBF) {
            const unsigned short* ap = ebf + a_base + ks * 32;
            pa0 = *(const uintx4*)ap; pa1 = *(const uintx4*)(ap + 8);
        } else {
            const float* ap = emb + a_base + ks * 32;
            floatx4 f0 = *(const floatx4*)ap;
            floatx4 f1 = *(const floatx4*)(ap + 4);
            floatx4 f2 = *(const floatx4*)(ap + 8);
            floatx4 f3 = *(const floatx4*)(ap + 12);
            pa0 = (uintx4){pk2(f0.x,f0.y), pk2(f0.z,f0.w), pk2(f1.x,f1.y), pk2(f1.z,f1.w)};
            pa1 = (uintx4){pk2(f2.x,f2.y), pk2(f2.z,f2.w), pk2(f3.x,f3.y), pk2(f3.z,f3.w)};
        }
    };
    fetch(0);

    floatx4 acc[2][8];
#pragma unroll
    for (int i = 0; i < 2; ++i)
#pragma unroll
        for (int j = 0; j < 8; ++j) acc[i][j] = (floatx4){0.f, 0.f, 0.f, 0.f};

#pragma unroll
    for (int ks = 0; ks < 8; ++ks) {
        short* Al = Ab[ks & 1];
        short* Bl = Bb[ks & 1];
        *(uintx4*)(Al + lw) = pa0; *(uintx4*)(Al + lw + 8) = pa1;
        *(uintx4*)(Bl + lw) = pb0; *(uintx4*)(Bl + lw + 8) = pb1;
        __syncthreads();
        if (ks < 7) fetch(ks + 1);   // overlaps MFMA below
        short8 af0 = *(const short8*)(Al + (32 * w + col) * ROWPAD + q * 8);
        short8 af1 = *(const short8*)(Al + (32 * w + 16 + col) * ROWPAD + q * 8);
#pragma unroll
        for (int nt = 0; nt < 8; ++nt) {
            short8 bfr = *(const short8*)(Bl + (nt * 16 + col) * ROWPAD + q * 8);
            acc[0][nt] = __builtin_amdgcn_mfma_f32_16x16x32_bf16(af0, bfr, acc[0][nt], 0, 0, 0);
            acc[1][nt] = __builtin_amdgcn_mfma_f32_16x16x32_bf16(af1, bfr, acc[1][nt], 0, 0, 0);
        }
    }

    // Epilogue: t = (mt)*16 + q*4 + reg, h = nt*16 + col (z: nt, f: nt+4).
    // Compose c <- f*c + (1-f)*z over t: in-lane over regs, cross-quad via shfl_xor.
    const int hbase = hg * 64;
    float Afin[4], Bfin[4];
#pragma unroll
    for (int nt = 0; nt < 4; ++nt) {
        const float bz  = bq[hbase + nt * 16 + col];
        const float bff = bq[HDIM + hbase + nt * 16 + col];
        float Aseg[2], Bseg[2];
#pragma unroll
        for (int mt = 0; mt < 2; ++mt) {
            float Ac = 1.f, Bc = 0.f;
#pragma unroll
            for (int j = 0; j < 4; ++j) {
                float z = tanh_fast(acc[mt][nt][j] + bz);
                float f = sigm(acc[mt][nt + 4][j] + bff);
                Ac = f * Ac;
                Bc = fmaf(f, Bc, (1.f - f) * z);
            }
            Aseg[mt] = Ac; Bseg[mt] = Bc;
        }
#pragma unroll
        for (int s = 0; s < 2; ++s) {
            const int msk = 16 << s;
            const bool self_earlier = ((q >> s) & 1) == 0;
#pragma unroll
            for (int mt = 0; mt < 2; ++mt) {
                float Ap = __shfl_xor(Aseg[mt], msk, 64);
                float Bp = __shfl_xor(Bseg[mt], msk, 64);
                Bseg[mt] = self_earlier ? fmaf(Ap, Bseg[mt], Bp)
                                        : fmaf(Aseg[mt], Bp, Bseg[mt]);
                Aseg[mt] = Aseg[mt] * Ap;   // product commutes
            }
        }
        Afin[nt] = Aseg[0] * Aseg[1];
        Bfin[nt] = fmaf(Aseg[1], Bseg[0], Bseg[1]);
    }
    // quad q stores nt = q -> h = hbase + lane, fully coalesced
    float As = (q == 0) ? Afin[0] : (q == 1) ? Afin[1] : (q == 2) ? Afin[2] : Afin[3];
    float Bs = (q == 0) ? Bfin[0] : (q == 1) ? Bfin[1] : (q == 2) ? Bfin[2] : Bfin[3];
    const int b = bg * 4 + w;
    const size_t base = ((size_t)chunk * BDIM + b) * HDIM + hbase + lane;
    wsA[base] = As;
    wsB[base] = Bs;
}

// Kernel 2 (unchanged from round 1, proven): combine chunks + o-gate + output dot.
__global__ __launch_bounds__(256) void qrnn_combine(
    const float* __restrict__ wsA, const float* __restrict__ wsB,
    const float* __restrict__ c0, const int* __restrict__ X,
    const float* __restrict__ emb, const float* __restrict__ Wq,
    const float* __restrict__ bq, const float* __restrict__ Wout,
    const float* __restrict__ bout, float* __restrict__ out)
{
    const int b = blockIdx.x;
    const int h = threadIdx.x;

    float c = c0[b * HDIM + h];
    for (int ci = 0; ci < NC; ++ci) {
        size_t base = ((size_t)ci * BDIM + b) * HDIM + h;
        c = fmaf(wsA[base], c, wsB[base]);
    }

    __shared__ float xs[EDIM];
    int idx = X[b * TDIM + (TDIM - 1)];
    xs[h] = emb[(size_t)idx * EDIM + h];
    __syncthreads();

    float acc = 0.f;
#pragma unroll 8
    for (int e = 0; e < EDIM; ++e)
        acc = fmaf(xs[e], Wq[e * (3 * HDIM) + 2 * HDIM + h], acc);

    float o  = 1.f / (1.f + expf(-(acc + bq[2 * HDIM + h])));
    float hn = o * c;

    __shared__ float red[HDIM];
    red[h] = hn * Wout[h];
    __syncthreads();
    for (int s = HDIM / 2; s > 0; s >>= 1) {
        if (h < s) red[h] += red[h + s];
        __syncthreads();
    }
    if (h == 0) out[b] = red[0] + bout[0];
}

extern "C" void kernel_launch(void* const* d_in, const int* in_sizes, int n_in,
                              void* d_out, int out_size, void* d_ws, size_t ws_size,
                              hipStream_t stream) {
    const int*   X    = (const int*)d_in[0];
    const float* emb  = (const float*)d_in[1];
    const float* Wq   = (const float*)d_in[2];
    const float* bq   = (const float*)d_in[3];
    const float* c0   = (const float*)d_in[4];
    const float* Wout = (const float*)d_in[5];
    const float* bout = (const float*)d_in[6];
    float* out = (float*)d_out;

    float* wsA = (float*)d_ws;
    float* wsB = wsA + (size_t)NC * BDIM * HDIM;
    unsigned short* Wt  = (unsigned short*)(wsB + (size_t)NC * BDIM * HDIM);
    unsigned short* ebf = Wt + 512 * EDIM;

    const size_t need_full = (size_t)2 * NC * BDIM * HDIM * 4
                           + (size_t)512 * EDIM * 2
                           + (size_t)32000 * EDIM * 2;
    const bool full = ws_size >= need_full;

    conv_w<<<512, 256, 0, stream>>>(Wq, Wt);
    if (full)
        conv_emb<<<(32000 * EDIM / 4) / 256, 256, 0, stream>>>(emb, ebf);

    dim3 g(NC, BDIM / 4, HDIM / 64);
    if (full) qrnn_mfma<true ><<<g, 256, 0, stream>>>(X, emb, ebf, Wt, bq, wsA, wsB);
    else      qrnn_mfma<false><<<g, 256, 0, stream>>>(X, emb, ebf, Wt, bq, wsA, wsB);

    qrnn_combine<<<BDIM, 256, 0, stream>>>(wsA, wsB, c0, X, emb, Wq, bq, Wout, bout, out);
}

// Round 3
// 169.426 us; speedup vs baseline: 3.9325x; 1.0888x over previous
//
#include <hip/hip_runtime.h>
#include <hip/hip_bf16.h>
#include <math.h>

#define EDIM 256
#define HDIM 256
#define BDIM 64
#define TDIM 2048
#define NC   64
#define TC   32

typedef __attribute__((ext_vector_type(8)))  short  short8;
typedef __attribute__((ext_vector_type(4)))  float  floatx4;
typedef __attribute__((ext_vector_type(4)))  unsigned int uintx4;

__device__ __forceinline__ unsigned short f2bf(float f) {
    unsigned int u = __float_as_uint(f);
    u += 0x7FFFu + ((u >> 16) & 1u);      // RNE
    return (unsigned short)(u >> 16);
}
__device__ __forceinline__ unsigned int pk2(float a, float b) {
    return (unsigned int)f2bf(a) | ((unsigned int)f2bf(b) << 16);
}
__device__ __forceinline__ float sigm(float x) {
    return __builtin_amdgcn_rcpf(1.f + __expf(-x));
}
__device__ __forceinline__ float tanh_fast(float x) {
    return fmaf(-2.f, __builtin_amdgcn_rcpf(1.f + __expf(2.f * x)), 1.f);
}

// Wp fragment-packed weights: [hg][nt][ks][lane][8] bf16.
// value = Wq[(ks*32 + q*8 + j) * 768 + c], c = z: hg*64+nt*16+col, f: 256+...
__global__ __launch_bounds__(256) void conv_wp(const float* __restrict__ Wq,
                                               unsigned short* __restrict__ Wp) {
    const int bx = blockIdx.x;               // hg*64 + nt*8 + ks
    const int nt = (bx >> 3) & 7;
    const int hg = bx >> 6;
    const int ks = bx & 7;
    const int t = threadIdx.x;
    const int lane = t >> 2, pj = t & 3;
    const int col = lane & 15, q = lane >> 4;
    const int h = hg * 64 + (nt & 3) * 16 + col;
    const int c = (nt < 4) ? h : (HDIM + h);
    const int k = ks * 32 + q * 8 + pj * 2;
    unsigned int v = pk2(Wq[k * (3 * HDIM) + c], Wq[(k + 1) * (3 * HDIM) + c]);
    *(unsigned int*)(Wp + (size_t)bx * 512 + lane * 8 + pj * 2) = v;
}

__global__ __launch_bounds__(256) void conv_emb(const float* __restrict__ emb,
                                                unsigned short* __restrict__ ebf) {
    size_t i = ((size_t)blockIdx.x * 256 + threadIdx.x) * 8;
    floatx4 a = *(const floatx4*)(emb + i);
    floatx4 b = *(const floatx4*)(emb + i + 4);
    uintx4 o = {pk2(a.x, a.y), pk2(a.z, a.w), pk2(b.x, b.y), pk2(b.z, b.w)};
    *(uintx4*)(ebf + i) = o;
}

// Main: block = 4 waves; wave owns 2 batches (64 m) x 128 n (64 h: z+f).
// B: all-ks fragment-packed slice staged ONCE to LDS via global_load_lds;
// A: per-lane direct gather from bf16 emb. K-loop is barrier-free.
template<bool EMBBF>
__global__ __launch_bounds__(256, 2) void qrnn_mfma(
    const int* __restrict__ X, const float* __restrict__ emb,
    const unsigned short* __restrict__ ebf, const unsigned short* __restrict__ Wp,
    const float* __restrict__ bq, float* __restrict__ wsA, float* __restrict__ wsB)
{
    __shared__ __align__(16) short Bs[32768];   // 64 KB: [nt][ks][64 lanes][8]

    const int tid = threadIdx.x;
    const int chunk = blockIdx.x, bg = blockIdx.y, hg = blockIdx.z;
    const int lane = tid & 63, w = tid >> 6;
    const int col = lane & 15, q = lane >> 4;
    const int t0 = chunk * TC;

    // Stage B (64 KB, all ks): wave w stages 16 of the 64 1-KB chunks.
    const unsigned short* wpb = Wp + (size_t)hg * 64 * 512;
#pragma unroll
    for (int i = 0; i < 16; ++i) {
        const int ch = w * 16 + i;          // wave-uniform
        __builtin_amdgcn_global_load_lds(
            (const __attribute__((address_space(1))) unsigned int*)(wpb + ch * 512 + lane * 8),
            (__attribute__((address_space(3))) unsigned int*)(Bs + ch * 512),
            16, 0, 0);
    }

    // A row pointers (overlap with B staging): wave owns batches b0, b0+1.
    const int b0 = bg * 8 + 2 * w;
    int xid[4];
#pragma unroll
    for (int mt = 0; mt < 4; ++mt)
        xid[mt] = X[(b0 + (mt >> 1)) * TDIM + t0 + (mt & 1) * 16 + col];

    const unsigned short* ap[4];
    const float* apf[4];
#pragma unroll
    for (int mt = 0; mt < 4; ++mt) {
        if constexpr (EMBBF) ap[mt]  = ebf + (size_t)xid[mt] * EDIM + q * 8;
        else                 apf[mt] = emb + (size_t)xid[mt] * EDIM + q * 8;
    }

    floatx4 acc[4][8];
#pragma unroll
    for (int mt = 0; mt < 4; ++mt)
#pragma unroll
        for (int nt = 0; nt < 8; ++nt) acc[mt][nt] = (floatx4){0.f, 0.f, 0.f, 0.f};

    __syncthreads();   // B staged (sync waits vmcnt too)

#pragma unroll
    for (int ks = 0; ks < 8; ++ks) {
        short8 af[4];
#pragma unroll
        for (int mt = 0; mt < 4; ++mt) {
            if constexpr (EMBBF) {
                af[mt] = *(const short8*)(ap[mt] + ks * 32);
            } else {
                floatx4 f0 = *(const floatx4*)(apf[mt] + ks * 32);
                floatx4 f1 = *(const floatx4*)(apf[mt] + ks * 32 + 4);
                uintx4 p = {pk2(f0.x, f0.y), pk2(f0.z, f0.w),
                            pk2(f1.x, f1.y), pk2(f1.z, f1.w)};
                af[mt] = *(short8*)&p;
            }
        }
        short8 bf[8];
#pragma unroll
        for (int nt = 0; nt < 8; ++nt)
            bf[nt] = *(const short8*)(Bs + (nt * 8 + ks) * 512 + lane * 8);
#pragma unroll
        for (int nt = 0; nt < 8; ++nt)
#pragma unroll
            for (int mt = 0; mt < 4; ++mt)
                acc[mt][nt] = __builtin_amdgcn_mfma_f32_16x16x32_bf16(af[mt], bf[nt], acc[mt][nt], 0, 0, 0);
    }

    // Epilogue: C/D layout: n-col = nt*16+col, m-row t = q*4 + j (+16*(mt&1)).
    const int hbase = hg * 64;
    float bz[4], bff[4];
#pragma unroll
    for (int nt = 0; nt < 4; ++nt) {
        bz[nt]  = bq[hbase + nt * 16 + col];
        bff[nt] = bq[HDIM + hbase + nt * 16 + col];
    }

    float Af0[4], Bf0[4], Af1[4], Bf1[4];
#pragma unroll
    for (int nt = 0; nt < 4; ++nt) {
        float Aseg[4], Bseg[4];
#pragma unroll
        for (int mt = 0; mt < 4; ++mt) {
            float Ac = 1.f, Bc = 0.f;
#pragma unroll
            for (int j = 0; j < 4; ++j) {
                float z = tanh_fast(acc[mt][nt][j] + bz[nt]);
                float f = sigm(acc[mt][nt + 4][j] + bff[nt]);
                Ac = f * Ac;
                Bc = fmaf(f, Bc, (1.f - f) * z);
            }
            Aseg[mt] = Ac; Bseg[mt] = Bc;
        }
#pragma unroll
        for (int s = 0; s < 2; ++s) {
            const int msk = 16 << s;
            const bool self_earlier = ((q >> s) & 1) == 0;
#pragma unroll
            for (int mt = 0; mt < 4; ++mt) {
                float Ap = __shfl_xor(Aseg[mt], msk, 64);
                float Bp = __shfl_xor(Bseg[mt], msk, 64);
                Bseg[mt] = self_earlier ? fmaf(Ap, Bseg[mt], Bp)
                                        : fmaf(Aseg[mt], Bp, Bseg[mt]);
                Aseg[mt] = Aseg[mt] * Ap;
            }
        }
        Af0[nt] = Aseg[0] * Aseg[1];
        Bf0[nt] = fmaf(Aseg[1], Bseg[0], Bseg[1]);
        Af1[nt] = Aseg[2] * Aseg[3];
        Bf1[nt] = fmaf(Aseg[3], Bseg[2], Bseg[3]);
    }

    float As0 = (q == 0) ? Af0[0] : (q == 1) ? Af0[1] : (q == 2) ? Af0[2] : Af0[3];
    float Bs0 = (q == 0) ? Bf0[0] : (q == 1) ? Bf0[1] : (q == 2) ? Bf0[2] : Bf0[3];
    float As1 = (q == 0) ? Af1[0] : (q == 1) ? Af1[1] : (q == 2) ? Af1[2] : Af1[3];
    float Bs1 = (q == 0) ? Bf1[0] : (q == 1) ? Bf1[1] : (q == 2) ? Bf1[2] : Bf1[3];

    const size_t r0 = ((size_t)chunk * BDIM + b0) * HDIM + hbase + lane;
    wsA[r0] = As0;          wsB[r0] = Bs0;
    wsA[r0 + HDIM] = As1;   wsB[r0 + HDIM] = Bs1;
}

// Combine chunk (A,B) pairs (batched loads to break latency serialization),
// o-gate at t=T-1, output dot.
__global__ __launch_bounds__(256) void qrnn_combine(
    const float* __restrict__ wsA, const float* __restrict__ wsB,
    const float* __restrict__ c0, const int* __restrict__ X,
    const float* __restrict__ emb, const float* __restrict__ Wq,
    const float* __restrict__ bq, const float* __restrict__ Wout,
    const float* __restrict__ bout, float* __restrict__ out)
{
    const int b = blockIdx.x;
    const int h = threadIdx.x;

    float c = c0[b * HDIM + h];
    for (int c8 = 0; c8 < NC; c8 += 8) {
        float a[8], bb[8];
#pragma unroll
        for (int i = 0; i < 8; ++i) {
            size_t base = ((size_t)(c8 + i) * BDIM + b) * HDIM + h;
            a[i]  = wsA[base];
            bb[i] = wsB[base];
        }
#pragma unroll
        for (int i = 0; i < 8; ++i) c = fmaf(a[i], c, bb[i]);
    }

    __shared__ float xs[EDIM];
    int idx = X[b * TDIM + (TDIM - 1)];
    xs[h] = emb[(size_t)idx * EDIM + h];
    __syncthreads();

    float acc = 0.f;
#pragma unroll 16
    for (int e = 0; e < EDIM; ++e)
        acc = fmaf(xs[e], Wq[e * (3 * HDIM) + 2 * HDIM + h], acc);

    float o  = 1.f / (1.f + expf(-(acc + bq[2 * HDIM + h])));
    float hn = o * c;

    __shared__ float red[HDIM];
    red[h] = hn * Wout[h];
    __syncthreads();
    for (int s = HDIM / 2; s > 0; s >>= 1) {
        if (h < s) red[h] += red[h + s];
        __syncthreads();
    }
    if (h == 0) out[b] = red[0] + bout[0];
}

extern "C" void kernel_launch(void* const* d_in, const int* in_sizes, int n_in,
                              void* d_out, int out_size, void* d_ws, size_t ws_size,
                              hipStream_t stream) {
    const int*   X    = (const int*)d_in[0];
    const float* emb  = (const float*)d_in[1];
    const float* Wq   = (const float*)d_in[2];
    const float* bq   = (const float*)d_in[3];
    const float* c0   = (const float*)d_in[4];
    const float* Wout = (const float*)d_in[5];
    const float* bout = (const float*)d_in[6];
    float* out = (float*)d_out;

    float* wsA = (float*)d_ws;                        // [NC][B][H]
    float* wsB = wsA + (size_t)NC * BDIM * HDIM;      // [NC][B][H]
    unsigned short* Wp  = (unsigned short*)(wsB + (size_t)NC * BDIM * HDIM);  // 256 KB
    unsigned short* ebf = Wp + (size_t)256 * 512;     // 16.4 MB

    const size_t need_full = (size_t)2 * NC * BDIM * HDIM * 4
                           + (size_t)256 * 512 * 2
                           + (size_t)32000 * EDIM * 2;
    const bool full = ws_size >= need_full;

    conv_wp<<<256, 256, 0, stream>>>(Wq, Wp);
    if (full)
        conv_emb<<<(32000 * EDIM / 8) / 256, 256, 0, stream>>>(emb, ebf);

    dim3 g(NC, BDIM / 8, HDIM / 64);   // 64 x 8 x 4 = 2048 blocks
    if (full) qrnn_mfma<true ><<<g, 256, 0, stream>>>(X, emb, ebf, Wp, bq, wsA, wsB);
    else      qrnn_mfma<false><<<g, 256, 0, stream>>>(X, emb, ebf, Wp, bq, wsA, wsB);

    qrnn_combine<<<BDIM, 256, 0, stream>>>(wsA, wsB, c0, X, emb, Wq, bq, Wout, bout, out);
}

// Round 4
// 149.953 us; speedup vs baseline: 4.4432x; 1.1299x over previous
//
#include <hip/hip_runtime.h>
#include <hip/hip_bf16.h>
#include <math.h>

#define EDIM 256
#define HDIM 256
#define BDIM 64
#define TDIM 2048
#define NC   64
#define TC   32
#define CPB  4      // chunks per persistent block

typedef __attribute__((ext_vector_type(8)))  short  short8;
typedef __attribute__((ext_vector_type(4)))  float  floatx4;
typedef __attribute__((ext_vector_type(4)))  unsigned int uintx4;

__device__ __forceinline__ unsigned short f2bf(float f) {
    unsigned int u = __float_as_uint(f);
    u += 0x7FFFu + ((u >> 16) & 1u);      // RNE
    return (unsigned short)(u >> 16);
}
__device__ __forceinline__ unsigned int pk2(float a, float b) {
    return (unsigned int)f2bf(a) | ((unsigned int)f2bf(b) << 16);
}
__device__ __forceinline__ float sigm(float x) {
    return __builtin_amdgcn_rcpf(1.f + __expf(-x));
}
__device__ __forceinline__ float tanh_fast(float x) {
    return fmaf(-2.f, __builtin_amdgcn_rcpf(1.f + __expf(2.f * x)), 1.f);
}

// Fused pack: blocks [0,256) -> Wp fragment-pack; blocks [256,4256) -> emb bf16.
// Wp layout: [hg][nt][ks][lane][8] bf16; value = Wq[(ks*32+q*8+j)*768 + c],
// c = z: hg*64+(nt&3)*16+col, f: 256 + same.
__global__ __launch_bounds__(256) void qrnn_pack(
    const float* __restrict__ Wq, const float* __restrict__ emb,
    unsigned short* __restrict__ Wp, unsigned short* __restrict__ ebf)
{
    const int bx = blockIdx.x;
    if (bx < 256) {
        const int nt = (bx >> 3) & 7;
        const int hg = bx >> 6;
        const int ks = bx & 7;
        const int t = threadIdx.x;
        const int lane = t >> 2, pj = t & 3;
        const int col = lane & 15, q = lane >> 4;
        const int h = hg * 64 + (nt & 3) * 16 + col;
        const int c = (nt < 4) ? h : (HDIM + h);
        const int k = ks * 32 + q * 8 + pj * 2;
        unsigned int v = pk2(Wq[k * (3 * HDIM) + c], Wq[(k + 1) * (3 * HDIM) + c]);
        *(unsigned int*)(Wp + (size_t)bx * 512 + lane * 8 + pj * 2) = v;
    } else {
        size_t i = ((size_t)(bx - 256) * 256 + threadIdx.x) * 8;
        floatx4 a = *(const floatx4*)(emb + i);
        floatx4 b = *(const floatx4*)(emb + i + 4);
        uintx4 o = {pk2(a.x, a.y), pk2(a.z, a.w), pk2(b.x, b.y), pk2(b.z, b.w)};
        *(uintx4*)(ebf + i) = o;
    }
}

// Main: persistent block = 4 chunks x 8 batches x 64 h (128 n-cols).
// B (weights) staged to LDS ONCE per block; chunk loop is barrier-free.
// A gathered per-lane from bf16 emb with a 3-slot (2-ahead) software pipeline
// that crosses chunk boundaries.
template<bool EMBBF>
__global__ __launch_bounds__(256, 2) void qrnn_mfma(
    const int* __restrict__ X, const float* __restrict__ emb,
    const unsigned short* __restrict__ ebf, const unsigned short* __restrict__ Wp,
    const float* __restrict__ bq, float* __restrict__ wsA, float* __restrict__ wsB)
{
    __shared__ __align__(16) short Bsh[32768];   // 64 KB: [nt][ks][64 lanes][8]

    const int tid = threadIdx.x;
    const int cg = blockIdx.x, bg = blockIdx.y, hg = blockIdx.z;
    const int lane = tid & 63, w = tid >> 6;
    const int col = lane & 15, q = lane >> 4;

    // Stage B slice (64 KB, all ks) once.
    const unsigned short* wpb = Wp + (size_t)hg * 32768;
#pragma unroll
    for (int i = 0; i < 16; ++i) {
        const int ch = w * 16 + i;          // wave-uniform
        __builtin_amdgcn_global_load_lds(
            (const __attribute__((address_space(1))) unsigned int*)(wpb + ch * 512 + lane * 8),
            (__attribute__((address_space(3))) unsigned int*)(Bsh + ch * 512),
            16, 0, 0);
    }

    const int b0 = bg * 8 + 2 * w;
    int xid[CPB][4];
#pragma unroll
    for (int c = 0; c < CPB; ++c)
#pragma unroll
        for (int mt = 0; mt < 4; ++mt)
            xid[c][mt] = X[(b0 + (mt >> 1)) * TDIM + (cg * CPB + c) * TC + (mt & 1) * 16 + col];

    const int hbase = hg * 64;
    float bz[4], bff[4];
#pragma unroll
    for (int nt = 0; nt < 4; ++nt) {
        bz[nt]  = bq[hbase + nt * 16 + col];
        bff[nt] = bq[HDIM + hbase + nt * 16 + col];
    }

    short8 abuf[3][4];
    auto fetchA = [&](int c, int ks, int slot) {
#pragma unroll
        for (int mt = 0; mt < 4; ++mt) {
            if constexpr (EMBBF) {
                abuf[slot][mt] = *(const short8*)(ebf + (size_t)xid[c][mt] * EDIM + q * 8 + ks * 32);
            } else {
                const float* ap = emb + (size_t)xid[c][mt] * EDIM + q * 8 + ks * 32;
                floatx4 f0 = *(const floatx4*)ap;
                floatx4 f1 = *(const floatx4*)(ap + 4);
                uintx4 p = {pk2(f0.x, f0.y), pk2(f0.z, f0.w),
                            pk2(f1.x, f1.y), pk2(f1.z, f1.w)};
                abuf[slot][mt] = *(short8*)&p;
            }
        }
    };

    floatx4 acc[4][8];
#pragma unroll
    for (int mt = 0; mt < 4; ++mt)
#pragma unroll
        for (int nt = 0; nt < 8; ++nt) acc[mt][nt] = (floatx4){0.f, 0.f, 0.f, 0.f};

    fetchA(0, 0, 0);
    fetchA(0, 1, 1);
    __syncthreads();   // waits staging vmem too

#pragma unroll
    for (int c = 0; c < CPB; ++c) {
#pragma unroll
        for (int ks = 0; ks < 8; ++ks) {
            const int s = c * 8 + ks;
            if (s + 2 < CPB * 8)
                fetchA((s + 2) >> 3, (s + 2) & 7, (s + 2) % 3);
            short8 bf[8];
#pragma unroll
            for (int nt = 0; nt < 8; ++nt)
                bf[nt] = *(const short8*)(Bsh + (nt * 8 + ks) * 512 + lane * 8);
            const int sl = s % 3;
#pragma unroll
            for (int nt = 0; nt < 8; ++nt)
#pragma unroll
                for (int mt = 0; mt < 4; ++mt)
                    acc[mt][nt] = __builtin_amdgcn_mfma_f32_16x16x32_bf16(abuf[sl][mt], bf[nt], acc[mt][nt], 0, 0, 0);
        }

        // Epilogue for chunk cc: t = q*4 + j (+16*(mt&1)), h-col = nt*16+col.
        const int cc = cg * CPB + c;
        float Af0[4], Bf0[4], Af1[4], Bf1[4];
#pragma unroll
        for (int nt = 0; nt < 4; ++nt) {
            float Aseg[4], Bseg[4];
#pragma unroll
            for (int mt = 0; mt < 4; ++mt) {
                float Ac = 1.f, Bc = 0.f;
#pragma unroll
                for (int j = 0; j < 4; ++j) {
                    float z = tanh_fast(acc[mt][nt][j] + bz[nt]);
                    float f = sigm(acc[mt][nt + 4][j] + bff[nt]);
                    Ac = f * Ac;
                    Bc = fmaf(f, Bc, (1.f - f) * z);
                }
                Aseg[mt] = Ac; Bseg[mt] = Bc;
            }
#pragma unroll
            for (int st = 0; st < 2; ++st) {
                const int msk = 16 << st;
                const bool self_earlier = ((q >> st) & 1) == 0;
#pragma unroll
                for (int mt = 0; mt < 4; ++mt) {
                    float Ap = __shfl_xor(Aseg[mt], msk, 64);
                    float Bp = __shfl_xor(Bseg[mt], msk, 64);
                    Bseg[mt] = self_earlier ? fmaf(Ap, Bseg[mt], Bp)
                                            : fmaf(Aseg[mt], Bp, Bseg[mt]);
                    Aseg[mt] = Aseg[mt] * Ap;
                }
            }
            Af0[nt] = Aseg[0] * Aseg[1];
            Bf0[nt] = fmaf(Aseg[1], Bseg[0], Bseg[1]);
            Af1[nt] = Aseg[2] * Aseg[3];
            Bf1[nt] = fmaf(Aseg[3], Bseg[2], Bseg[3]);
        }

        float As0 = (q == 0) ? Af0[0] : (q == 1) ? Af0[1] : (q == 2) ? Af0[2] : Af0[3];
        float Bs0 = (q == 0) ? Bf0[0] : (q == 1) ? Bf0[1] : (q == 2) ? Bf0[2] : Bf0[3];
        float As1 = (q == 0) ? Af1[0] : (q == 1) ? Af1[1] : (q == 2) ? Af1[2] : Af1[3];
        float Bs1 = (q == 0) ? Bf1[0] : (q == 1) ? Bf1[1] : (q == 2) ? Bf1[2] : Bf1[3];

        const size_t r0 = ((size_t)cc * BDIM + b0) * HDIM + hbase + lane;
        wsA[r0] = As0;          wsB[r0] = Bs0;
        wsA[r0 + HDIM] = As1;   wsB[r0 + HDIM] = Bs1;

#pragma unroll
        for (int mt = 0; mt < 4; ++mt)
#pragma unroll
            for (int nt = 0; nt < 8; ++nt) acc[mt][nt] = (floatx4){0.f, 0.f, 0.f, 0.f};
    }
}

// Combine chunk (A,B) pairs + o-gate at t=T-1 + output dot.
__global__ __launch_bounds__(256) void qrnn_combine(
    const float* __restrict__ wsA, const float* __restrict__ wsB,
    const float* __restrict__ c0, const int* __restrict__ X,
    const float* __restrict__ emb, const float* __restrict__ Wq,
    const float* __restrict__ bq, const float* __restrict__ Wout,
    const float* __restrict__ bout, float* __restrict__ out)
{
    const int b = blockIdx.x;
    const int h = threadIdx.x;

    float c = c0[b * HDIM + h];
    for (int c8 = 0; c8 < NC; c8 += 8) {
        float a[8], bb[8];
#pragma unroll
        for (int i = 0; i < 8; ++i) {
            size_t base = ((size_t)(c8 + i) * BDIM + b) * HDIM + h;
            a[i]  = wsA[base];
            bb[i] = wsB[base];
        }
#pragma unroll
        for (int i = 0; i < 8; ++i) c = fmaf(a[i], c, bb[i]);
    }

    __shared__ float xs[EDIM];
    int idx = X[b * TDIM + (TDIM - 1)];
    xs[h] = emb[(size_t)idx * EDIM + h];
    __syncthreads();

    float acc = 0.f;
#pragma unroll 16
    for (int e = 0; e < EDIM; ++e)
        acc = fmaf(xs[e], Wq[e * (3 * HDIM) + 2 * HDIM + h], acc);

    float o  = 1.f / (1.f + expf(-(acc + bq[2 * HDIM + h])));
    float hn = o * c;

    __shared__ float red[HDIM];
    red[h] = hn * Wout[h];
    __syncthreads();
    for (int s = HDIM / 2; s > 0; s >>= 1) {
        if (h < s) red[h] += red[h + s];
        __syncthreads();
    }
    if (h == 0) out[b] = red[0] + bout[0];
}

extern "C" void kernel_launch(void* const* d_in, const int* in_sizes, int n_in,
                              void* d_out, int out_size, void* d_ws, size_t ws_size,
                              hipStream_t stream) {
    const int*   X    = (const int*)d_in[0];
    const float* emb  = (const float*)d_in[1];
    const float* Wq   = (const float*)d_in[2];
    const float* bq   = (const float*)d_in[3];
    const float* c0   = (const float*)d_in[4];
    const float* Wout = (const float*)d_in[5];
    const float* bout = (const float*)d_in[6];
    float* out = (float*)d_out;

    float* wsA = (float*)d_ws;                        // [NC][B][H]
    float* wsB = wsA + (size_t)NC * BDIM * HDIM;      // [NC][B][H]
    unsigned short* Wp  = (unsigned short*)(wsB + (size_t)NC * BDIM * HDIM);  // 256 KB
    unsigned short* ebf = Wp + (size_t)256 * 512;     // 16.4 MB

    const size_t need_full = (size_t)2 * NC * BDIM * HDIM * 4
                           + (size_t)256 * 512 * 2
                           + (size_t)32000 * EDIM * 2;
    const bool full = ws_size >= need_full;

    const int emb_blocks = (32000 * EDIM / 8) / 256;   // 4000
    qrnn_pack<<<256 + (full ? emb_blocks : 0), 256, 0, stream>>>(Wq, emb, Wp, ebf);

    dim3 g(NC / CPB, BDIM / 8, HDIM / 64);   // 16 x 8 x 4 = 512 blocks (2/CU)
    if (full) qrnn_mfma<true ><<<g, 256, 0, stream>>>(X, emb, ebf, Wp, bq, wsA, wsB);
    else      qrnn_mfma<false><<<g, 256, 0, stream>>>(X, emb, ebf, Wp, bq, wsA, wsB);

    qrnn_combine<<<BDIM, 256, 0, stream>>>(wsA, wsB, c0, X, emb, Wq, bq, Wout, bout, out);
}